// Round 15
// baseline (365.535 us; speedup 1.0000x reference)
//
#include <hip/hip_runtime.h>
#include <hip/hip_bf16.h>
#include <math.h>

typedef __bf16 bf16;
typedef __attribute__((ext_vector_type(8))) bf16 bf16x8;
typedef __attribute__((ext_vector_type(2))) bf16 bf16x2;
typedef __attribute__((ext_vector_type(16))) float f32x16;
typedef __attribute__((ext_vector_type(4))) unsigned int uint4v;

#define SQ 2048
#define DH 64
#define NH 16
#define KVT 32
#define NKVT (SQ / KVT)          // 64 tiles per bh
#define REC 8192                 // per-tile record: 4KB K-frags + 4KB V-frags
#define LOG2E 1.44269504088896340736f
#define NHEAVY 6                 // heads 10..15: full/near-full bands
#define HEAVY_BLOCKS (NHEAVY * 64)        // 384
#define LIGHT_BLOCKS ((NH - NHEAVY) * 64 / 2)  // 320

__device__ __forceinline__ float fast_exp2(float x) {
#if __has_builtin(__builtin_amdgcn_exp2f)
    return __builtin_amdgcn_exp2f(x);
#else
    return exp2f(x);
#endif
}

__device__ __forceinline__ unsigned pkbf16(float a, float b) {
    union { bf16x2 h; unsigned u; } x;
    x.h = (bf16x2){(bf16)a, (bf16)b};
    return x.u;
}

#if __has_builtin(__builtin_amdgcn_permlane32_swap)
__device__ __forceinline__ void plswap(unsigned &a, unsigned &b) {
    typedef __attribute__((ext_vector_type(2))) unsigned int uint2v;
    uint2v r = __builtin_amdgcn_permlane32_swap(a, b, false, false);
    a = r[0]; b = r[1];
}
#else
__device__ __forceinline__ void plswap(unsigned &a, unsigned &b) {
    asm volatile("v_permlane32_swap_b32 %0, %1" : "+v"(a), "+v"(b));
}
#endif

union FragU { uint4v u; bf16x8 b; };

// ---------- prepass: write K and V as pre-fragmented 8KB tile records ----------
__global__ __launch_bounds__(256)
void alibi_prep_kernel(const float* __restrict__ K, const float* __restrict__ V,
                       char* __restrict__ W) {
    __shared__ bf16 lt[64][80];
    const int t  = threadIdx.x;
    const int s0 = blockIdx.x * 64;   // 64 kv rows = 2 tiles
    const int bh = blockIdx.y;
    if (blockIdx.z == 0) {
#pragma unroll
        for (int i = 0; i < 2; ++i) {
            const int g    = i * 256 + t;
            const int tile = g >> 8;
            const int cc   = g & 255;
            const int ds   = cc >> 6;
            const int lane = cc & 63;
            const float* p = K + ((size_t)bh * SQ + s0 + tile * 32 + (lane & 31)) * DH
                               + ds * 16 + (lane >> 5) * 8;
            float4 a = *(const float4*)p, b = *(const float4*)(p + 4);
            bf16x8 pk = {(bf16)a.x,(bf16)a.y,(bf16)a.z,(bf16)a.w,
                         (bf16)b.x,(bf16)b.y,(bf16)b.z,(bf16)b.w};
            *(bf16x8*)(W + (size_t)(bh * NKVT + (s0 >> 5) + tile) * REC
                         + ds * 1024 + lane * 16) = pk;
        }
    } else {
#pragma unroll
        for (int i = 0; i < 2; ++i) {
            int idx = i * 256 + t;
            int row = idx >> 3, c8 = idx & 7;
            const float* p = V + ((size_t)bh * SQ + s0 + row) * DH + c8 * 8;
            float4 a = *(const float4*)p, b = *(const float4*)(p + 4);
            bf16 e[8] = {(bf16)a.x,(bf16)a.y,(bf16)a.z,(bf16)a.w,
                         (bf16)b.x,(bf16)b.y,(bf16)b.z,(bf16)b.w};
#pragma unroll
            for (int jj = 0; jj < 8; ++jj) lt[c8 * 8 + jj][row] = e[jj];
        }
        __syncthreads();
#pragma unroll
        for (int i = 0; i < 2; ++i) {
            const int g    = i * 256 + t;
            const int tile = g >> 8;
            const int cc   = g & 255;
            const int grp  = cc >> 6;
            const int lane = cc & 63;
            const int d    = (grp >> 1) * 32 + (lane & 31);
            const int sv   = tile * 32 + (grp & 1) * 16 + (lane >> 5) * 8;
            bf16x8 v = *(const bf16x8*)&lt[d][sv];
            *(bf16x8*)(W + (size_t)(bh * NKVT + (s0 >> 5) + tile) * REC
                         + 4096 + grp * 1024 + lane * 16) = v;
        }
    }
}

// ---------- main attention: class-balanced work, 2-deep reg pipeline ----------
__global__ __launch_bounds__(512, 4)
void alibi_attn_kernel(const float* __restrict__ Q, const char* __restrict__ W,
                       float* __restrict__ Out) {
    __shared__ float ex[4][64][72];   // combine slots (73.7 KB), epilogue only
    const int tid  = threadIdx.x;
    const int lane = tid & 63;
    const int wave = tid >> 6;        // 0..7
    const int r32  = lane & 31;
    const int hi   = lane >> 5;

    // ---- class-balanced mapping ----
    // b < 384 (heavy, h=10..15): 8 waves on one (bh, 64q-chunk), kv parity 0..7.
    // b >= 384 (light, h=0..9): waves 0-3 and 4-7 each own a chunk, parity 0..3.
    const int B = blockIdx.x;         // 0..703
    const bool heavy = (B < HEAVY_BLOCKS);
    int h, bh, q0, par, lgs;
    if (heavy) {
        h   = 15 - (B >> 6);
        const int sub = B & 63;
        bh  = (sub >> 5) * NH + h;
        q0  = (sub & 31) * 64;
        par = wave;
        lgs = 3;                      // stride 8
    } else {
        const int c = (B - HEAVY_BLOCKS) * 2 + (wave >> 2);
        h   = 9 - (c >> 6);           // descending: h=9 light blocks start first
        const int sub = c & 63;
        bh  = (sub >> 5) * NH + h;
        q0  = (sub & 31) * 64;
        par = wave & 3;
        lgs = 2;                      // stride 4
    }
    const int stride = 1 << lgs;

    const float slope2  = exp2f(-0.5f * (float)(h + 1)) * LOG2E;
    const float SLOPE2N = -slope2;
    const float QSCALE  = 0.125f * LOG2E;

    // ---- ALiBi band over 32-kv tiles for q in [q0, q0+64) ----
    const int D = (int)(24.0f / slope2);
    const int a0 = q0 - D;
    const int tmin = (a0 <= 0) ? 0 : (a0 >> 5);
    const int tmax = min(NKVT - 1, (q0 + 63 + D) >> 5);

    const float* Qp = Q + (size_t)bh * SQ * DH;
    float*       Op = Out + (size_t)bh * SQ * DH;
    const char*  rec = W + (size_t)bh * NKVT * REC;

    // Q fragments, two q-sets: A rows q0+r32, B rows q0+32+r32
    const int qrowA = q0 + r32;
    bf16x8 qfragA[4], qfragB[4];
#pragma unroll
    for (int ds = 0; ds < 4; ++ds) {
        const float* sa = Qp + (size_t)qrowA * DH + ds * 16 + hi * 8;
        float4 a = *(const float4*)sa, b = *(const float4*)(sa + 4);
        qfragA[ds] = (bf16x8){(bf16)(a.x*QSCALE),(bf16)(a.y*QSCALE),
                              (bf16)(a.z*QSCALE),(bf16)(a.w*QSCALE),
                              (bf16)(b.x*QSCALE),(bf16)(b.y*QSCALE),
                              (bf16)(b.z*QSCALE),(bf16)(b.w*QSCALE)};
        const float* sb = sa + 32 * DH;
        float4 c = *(const float4*)sb, d = *(const float4*)(sb + 4);
        qfragB[ds] = (bf16x8){(bf16)(c.x*QSCALE),(bf16)(c.y*QSCALE),
                              (bf16)(c.z*QSCALE),(bf16)(c.w*QSCALE),
                              (bf16)(d.x*QSCALE),(bf16)(d.y*QSCALE),
                              (bf16)(d.z*QSCALE),(bf16)(d.w*QSCALE)};
    }

    f32x16 oaccA[2], oaccB[2];
#pragma unroll
    for (int d2 = 0; d2 < 2; ++d2)
#pragma unroll
        for (int rr = 0; rr < 16; ++rr) { oaccA[d2][rr] = 0.f; oaccB[d2][rr] = 0.f; }
    float psA[4] = {0.f,0.f,0.f,0.f}, psB[4] = {0.f,0.f,0.f,0.f};
    const float qhA = (float)(qrowA - 4 * hi);

    auto LOADF = [&](bf16x8* kf, bf16x8* vf, int tt) {
        const char* rb = rec + (size_t)tt * REC + lane * 16;
#pragma unroll
        for (int ds = 0; ds < 4; ++ds) kf[ds] = *(const bf16x8*)(rb + ds * 1024);
#pragma unroll
        for (int g = 0; g < 4; ++g)    vf[g] = *(const bf16x8*)(rb + 4096 + g * 1024);
    };

    auto COMPUTE = [&](const bf16x8* kf, const bf16x8* vf, int tt) {
        const float gq0 = qhA - (float)(tt * KVT);
#pragma unroll
        for (int qs = 0; qs < 2; ++qs) {
            const bf16x8* qf = qs ? qfragB : qfragA;
            f32x16*       oa = qs ? oaccB  : oaccA;
            float*        ps = qs ? psB    : psA;
            const float   gq = qs ? gq0 + 32.f : gq0;

            f32x16 sacc;
#pragma unroll
            for (int rr = 0; rr < 16; ++rr) sacc[rr] = 0.f;
            __builtin_amdgcn_s_setprio(1);
#pragma unroll
            for (int ds = 0; ds < 4; ++ds)
                sacc = __builtin_amdgcn_mfma_f32_32x32x16_bf16(kf[ds], qf[ds], sacc, 0, 0, 0);
            __builtin_amdgcn_s_setprio(0);

            float p[16];
#pragma unroll
            for (int reg = 0; reg < 16; ++reg) {
                const int krel = (reg & 3) + 8 * (reg >> 2);
                float d = gq - (float)krel;
                float s2 = fmaf(SLOPE2N, fabsf(d), sacc[reg]);
                float e = fast_exp2(s2);
                p[reg] = e;
                ps[reg & 3] += e;
            }

            __builtin_amdgcn_s_setprio(1);
#pragma unroll
            for (int ks = 0; ks < 2; ++ks) {
                unsigned u0 = pkbf16(p[8 * ks + 0], p[8 * ks + 1]);
                unsigned u1 = pkbf16(p[8 * ks + 2], p[8 * ks + 3]);
                unsigned v0 = pkbf16(p[8 * ks + 4], p[8 * ks + 5]);
                unsigned v1 = pkbf16(p[8 * ks + 6], p[8 * ks + 7]);
                plswap(u0, v0);
                plswap(u1, v1);
                FragU pf; pf.u = (uint4v){u0, u1, v0, v1};
#pragma unroll
                for (int dblk = 0; dblk < 2; ++dblk)
                    oa[dblk] = __builtin_amdgcn_mfma_f32_32x32x16_bf16(vf[dblk * 2 + ks], pf.b, oa[dblk], 0, 0, 0);
            }
            __builtin_amdgcn_s_setprio(0);
        }
    };

    // ---- 2-deep software pipeline over my parity's tiles ----
    {
        bf16x8 kA[4], vA[4], kB[4], vB[4];
        int t = tmin + par;
        if (t <= tmax) {
            const int n = ((tmax - t) >> lgs) + 1;
            LOADF(kA, vA, t);
            int i = 0;
            while (i + 2 <= n) {
                LOADF(kB, vB, t + stride);
                asm volatile("s_waitcnt vmcnt(8)" ::: "memory");   // kA/vA landed
                __builtin_amdgcn_sched_barrier(0);
                COMPUTE(kA, vA, t);
                if (i + 2 < n) {
                    LOADF(kA, vA, t + 2 * stride);
                    asm volatile("s_waitcnt vmcnt(8)" ::: "memory"); // kB/vB landed
                } else {
                    asm volatile("s_waitcnt vmcnt(0)" ::: "memory");
                }
                __builtin_amdgcn_sched_barrier(0);
                COMPUTE(kB, vB, t + stride);
                t += 2 * stride; i += 2;
            }
            if (i < n) {
                asm volatile("s_waitcnt vmcnt(0)" ::: "memory");
                __builtin_amdgcn_sched_barrier(0);
                COMPUTE(kA, vA, t);
            }
        }
    }

    // ---- combine: heavy = 8-wave tree, light = per-group 4-wave tree ----
    float psumA = (psA[0] + psA[1]) + (psA[2] + psA[3]);
    psumA += __shfl_xor(psumA, 32);
    float psumB = (psB[0] + psB[1]) + (psB[2] + psB[3]);
    psumB += __shfl_xor(psumB, 32);

    auto WRITE = [&](int si) {
        float* s = &ex[si][lane][0];
#pragma unroll
        for (int dblk = 0; dblk < 2; ++dblk)
#pragma unroll
            for (int g2 = 0; g2 < 4; ++g2) {
                *(float4*)(s + dblk * 16 + g2 * 4) =
                    (float4){oaccA[dblk][4*g2+0], oaccA[dblk][4*g2+1],
                             oaccA[dblk][4*g2+2], oaccA[dblk][4*g2+3]};
                *(float4*)(s + 36 + dblk * 16 + g2 * 4) =
                    (float4){oaccB[dblk][4*g2+0], oaccB[dblk][4*g2+1],
                             oaccB[dblk][4*g2+2], oaccB[dblk][4*g2+3]};
            }
        s[32] = psumA;
        s[68] = psumB;
    };
    auto ADDIN = [&](int si) {
        const float* s = &ex[si][lane][0];
#pragma unroll
        for (int dblk = 0; dblk < 2; ++dblk)
#pragma unroll
            for (int g2 = 0; g2 < 4; ++g2) {
                float4 oa = *(const float4*)(s + dblk * 16 + g2 * 4);
                float4 ob = *(const float4*)(s + 36 + dblk * 16 + g2 * 4);
                oaccA[dblk][4*g2+0] += oa.x; oaccA[dblk][4*g2+1] += oa.y;
                oaccA[dblk][4*g2+2] += oa.z; oaccA[dblk][4*g2+3] += oa.w;
                oaccB[dblk][4*g2+0] += ob.x; oaccB[dblk][4*g2+1] += ob.y;
                oaccB[dblk][4*g2+2] += ob.z; oaccB[dblk][4*g2+3] += ob.w;
            }
        psumA += s[32];
        psumB += s[68];
    };

    const int sb4 = (wave >> 2) * 2;          // light group slot base
    // L1: odd parities write slot par>>1 (heavy: 0..3, light: sb4+0/1)
    if (par & 1) WRITE(heavy ? (par >> 1) : (sb4 + (par >> 1)));
    __syncthreads();
    if (!(par & 1)) ADDIN(heavy ? (par >> 1) : (sb4 + (par >> 1)));
    __syncthreads();
    // L2
    if (heavy ? (par == 2 || par == 6) : (par == 2)) WRITE(heavy ? (par >> 2) : sb4);
    __syncthreads();
    if (heavy ? (par == 0 || par == 4) : (par == 0)) ADDIN(heavy ? (par >> 2) : sb4);
    __syncthreads();
    // L3 (heavy only)
    if (heavy && par == 4) WRITE(0);
    __syncthreads();
    if (par == 0) {
        if (heavy) ADDIN(0);
        const float invA = 1.f / psumA;
        const float invB = 1.f / psumB;
#pragma unroll
        for (int dblk = 0; dblk < 2; ++dblk)
#pragma unroll
            for (int g2 = 0; g2 < 4; ++g2) {
                float4 oa = {oaccA[dblk][4*g2+0] * invA, oaccA[dblk][4*g2+1] * invA,
                             oaccA[dblk][4*g2+2] * invA, oaccA[dblk][4*g2+3] * invA};
                *(float4*)(Op + (size_t)qrowA * DH + dblk * 32 + g2 * 8 + hi * 4) = oa;
                float4 ob = {oaccB[dblk][4*g2+0] * invB, oaccB[dblk][4*g2+1] * invB,
                             oaccB[dblk][4*g2+2] * invB, oaccB[dblk][4*g2+3] * invB};
                *(float4*)(Op + (size_t)(qrowA + 32) * DH + dblk * 32 + g2 * 8 + hi * 4) = ob;
            }
    }
}

extern "C" void kernel_launch(void* const* d_in, const int* in_sizes, int n_in,
                              void* d_out, int out_size, void* d_ws, size_t ws_size,
                              hipStream_t stream) {
    const float* q = (const float*)d_in[0];
    const float* k = (const float*)d_in[1];
    const float* v = (const float*)d_in[2];
    float* out = (float*)d_out;
    char* W = (char*)d_ws;                    // 32 bh x 64 tiles x 8KB = 16 MB
    alibi_prep_kernel<<<dim3(SQ / 64, 2 * NH, 2), dim3(256), 0, stream>>>(k, v, W);
    alibi_attn_kernel<<<dim3(HEAVY_BLOCKS + LIGHT_BLOCKS), dim3(512), 0, stream>>>(q, W, out);
}

// Round 16
// 55.017 us; speedup vs baseline: 6.6440x; 6.6440x over previous
//
#include <hip/hip_runtime.h>
#include <hip/hip_bf16.h>
#include <math.h>

typedef __bf16 bf16;
typedef __attribute__((ext_vector_type(8))) bf16 bf16x8;
typedef __attribute__((ext_vector_type(2))) bf16 bf16x2;
typedef __attribute__((ext_vector_type(16))) float f32x16;
typedef __attribute__((ext_vector_type(4))) unsigned int uint4v;

#define SQ 2048
#define DH 64
#define NH 16
#define KVT 32
#define NKVT (SQ / KVT)          // 64 tiles per bh
#define REC 8192                 // per-tile record: 4KB K-frags + 4KB V-frags
#define LOG2E 1.44269504088896340736f
#define NHEAVY 6                 // heads 10..15: full/near-full bands
#define HEAVY_BLOCKS (NHEAVY * 64)        // 384
#define LIGHT_BLOCKS ((NH - NHEAVY) * 64 / 2)  // 320

__device__ __forceinline__ float fast_exp2(float x) {
#if __has_builtin(__builtin_amdgcn_exp2f)
    return __builtin_amdgcn_exp2f(x);
#else
    return exp2f(x);
#endif
}

__device__ __forceinline__ unsigned pkbf16(float a, float b) {
    union { bf16x2 h; unsigned u; } x;
    x.h = (bf16x2){(bf16)a, (bf16)b};
    return x.u;
}

#if __has_builtin(__builtin_amdgcn_permlane32_swap)
__device__ __forceinline__ void plswap(unsigned &a, unsigned &b) {
    typedef __attribute__((ext_vector_type(2))) unsigned int uint2v;
    uint2v r = __builtin_amdgcn_permlane32_swap(a, b, false, false);
    a = r[0]; b = r[1];
}
#else
__device__ __forceinline__ void plswap(unsigned &a, unsigned &b) {
    asm volatile("v_permlane32_swap_b32 %0, %1" : "+v"(a), "+v"(b));
}
#endif

union FragU { uint4v u; bf16x8 b; };

// ---------- prepass: write K and V as pre-fragmented 8KB tile records ----------
__global__ __launch_bounds__(256)
void alibi_prep_kernel(const float* __restrict__ K, const float* __restrict__ V,
                       char* __restrict__ W) {
    __shared__ bf16 lt[64][80];
    const int t  = threadIdx.x;
    const int s0 = blockIdx.x * 64;   // 64 kv rows = 2 tiles
    const int bh = blockIdx.y;
    if (blockIdx.z == 0) {
#pragma unroll
        for (int i = 0; i < 2; ++i) {
            const int g    = i * 256 + t;
            const int tile = g >> 8;
            const int cc   = g & 255;
            const int ds   = cc >> 6;
            const int lane = cc & 63;
            const float* p = K + ((size_t)bh * SQ + s0 + tile * 32 + (lane & 31)) * DH
                               + ds * 16 + (lane >> 5) * 8;
            float4 a = *(const float4*)p, b = *(const float4*)(p + 4);
            bf16x8 pk = {(bf16)a.x,(bf16)a.y,(bf16)a.z,(bf16)a.w,
                         (bf16)b.x,(bf16)b.y,(bf16)b.z,(bf16)b.w};
            *(bf16x8*)(W + (size_t)(bh * NKVT + (s0 >> 5) + tile) * REC
                         + ds * 1024 + lane * 16) = pk;
        }
    } else {
#pragma unroll
        for (int i = 0; i < 2; ++i) {
            int idx = i * 256 + t;
            int row = idx >> 3, c8 = idx & 7;
            const float* p = V + ((size_t)bh * SQ + s0 + row) * DH + c8 * 8;
            float4 a = *(const float4*)p, b = *(const float4*)(p + 4);
            bf16 e[8] = {(bf16)a.x,(bf16)a.y,(bf16)a.z,(bf16)a.w,
                         (bf16)b.x,(bf16)b.y,(bf16)b.z,(bf16)b.w};
#pragma unroll
            for (int jj = 0; jj < 8; ++jj) lt[c8 * 8 + jj][row] = e[jj];
        }
        __syncthreads();
#pragma unroll
        for (int i = 0; i < 2; ++i) {
            const int g    = i * 256 + t;
            const int tile = g >> 8;
            const int cc   = g & 255;
            const int grp  = cc >> 6;
            const int lane = cc & 63;
            const int d    = (grp >> 1) * 32 + (lane & 31);
            const int sv   = tile * 32 + (grp & 1) * 16 + (lane >> 5) * 8;
            bf16x8 v = *(const bf16x8*)&lt[d][sv];
            *(bf16x8*)(W + (size_t)(bh * NKVT + (s0 >> 5) + tile) * REC
                         + 4096 + grp * 1024 + lane * 16) = v;
        }
    }
}

// ---------- main attention: class-balanced work, 2-deep reg pipeline ----------
// launch_bounds 2nd arg behaves as blocks/CU-style cap on this toolchain:
// (512,4) capped VGPR at 64 and spilled 736MB (R15); (512,2) = 128-VGPR cap.
__global__ __launch_bounds__(512, 2)
void alibi_attn_kernel(const float* __restrict__ Q, const char* __restrict__ W,
                       float* __restrict__ Out) {
    __shared__ float ex[4][64][72];   // combine slots (73.7 KB), epilogue only
    const int tid  = threadIdx.x;
    const int lane = tid & 63;
    const int wave = tid >> 6;        // 0..7
    const int r32  = lane & 31;
    const int hi   = lane >> 5;

    // ---- class-balanced mapping ----
    // b < 384 (heavy, h=10..15): 8 waves on one (bh, 64q-chunk), kv parity 0..7.
    // b >= 384 (light, h=0..9): waves 0-3 and 4-7 each own a chunk, parity 0..3.
    const int B = blockIdx.x;         // 0..703
    const bool heavy = (B < HEAVY_BLOCKS);
    int h, bh, q0, par, lgs;
    if (heavy) {
        h   = 15 - (B >> 6);
        const int sub = B & 63;
        bh  = (sub >> 5) * NH + h;
        q0  = (sub & 31) * 64;
        par = wave;
        lgs = 3;                      // stride 8
    } else {
        const int c = (B - HEAVY_BLOCKS) * 2 + (wave >> 2);
        h   = 9 - (c >> 6);           // descending: h=9 light blocks start first
        const int sub = c & 63;
        bh  = (sub >> 5) * NH + h;
        q0  = (sub & 31) * 64;
        par = wave & 3;
        lgs = 2;                      // stride 4
    }
    const int stride = 1 << lgs;

    const float slope2  = exp2f(-0.5f * (float)(h + 1)) * LOG2E;
    const float SLOPE2N = -slope2;
    const float QSCALE  = 0.125f * LOG2E;

    // ---- ALiBi band over 32-kv tiles for q in [q0, q0+64) ----
    const int D = (int)(24.0f / slope2);
    const int a0 = q0 - D;
    const int tmin = (a0 <= 0) ? 0 : (a0 >> 5);
    const int tmax = min(NKVT - 1, (q0 + 63 + D) >> 5);

    const float* Qp = Q + (size_t)bh * SQ * DH;
    float*       Op = Out + (size_t)bh * SQ * DH;
    const char*  rec = W + (size_t)bh * NKVT * REC;

    // Q fragments, two q-sets: A rows q0+r32, B rows q0+32+r32
    const int qrowA = q0 + r32;
    bf16x8 qfragA[4], qfragB[4];
#pragma unroll
    for (int ds = 0; ds < 4; ++ds) {
        const float* sa = Qp + (size_t)qrowA * DH + ds * 16 + hi * 8;
        float4 a = *(const float4*)sa, b = *(const float4*)(sa + 4);
        qfragA[ds] = (bf16x8){(bf16)(a.x*QSCALE),(bf16)(a.y*QSCALE),
                              (bf16)(a.z*QSCALE),(bf16)(a.w*QSCALE),
                              (bf16)(b.x*QSCALE),(bf16)(b.y*QSCALE),
                              (bf16)(b.z*QSCALE),(bf16)(b.w*QSCALE)};
        const float* sb = sa + 32 * DH;
        float4 c = *(const float4*)sb, d = *(const float4*)(sb + 4);
        qfragB[ds] = (bf16x8){(bf16)(c.x*QSCALE),(bf16)(c.y*QSCALE),
                              (bf16)(c.z*QSCALE),(bf16)(c.w*QSCALE),
                              (bf16)(d.x*QSCALE),(bf16)(d.y*QSCALE),
                              (bf16)(d.z*QSCALE),(bf16)(d.w*QSCALE)};
    }

    f32x16 oaccA[2], oaccB[2];
#pragma unroll
    for (int d2 = 0; d2 < 2; ++d2)
#pragma unroll
        for (int rr = 0; rr < 16; ++rr) { oaccA[d2][rr] = 0.f; oaccB[d2][rr] = 0.f; }
    float psA[4] = {0.f,0.f,0.f,0.f}, psB[4] = {0.f,0.f,0.f,0.f};
    const float qhA = (float)(qrowA - 4 * hi);

    auto LOADF = [&](bf16x8* kf, bf16x8* vf, int tt) {
        const char* rb = rec + (size_t)tt * REC + lane * 16;
#pragma unroll
        for (int ds = 0; ds < 4; ++ds) kf[ds] = *(const bf16x8*)(rb + ds * 1024);
#pragma unroll
        for (int g = 0; g < 4; ++g)    vf[g] = *(const bf16x8*)(rb + 4096 + g * 1024);
    };

    auto COMPUTE = [&](const bf16x8* kf, const bf16x8* vf, int tt) {
        const float gq0 = qhA - (float)(tt * KVT);
#pragma unroll
        for (int qs = 0; qs < 2; ++qs) {
            const bf16x8* qf = qs ? qfragB : qfragA;
            f32x16*       oa = qs ? oaccB  : oaccA;
            float*        ps = qs ? psB    : psA;
            const float   gq = qs ? gq0 + 32.f : gq0;

            f32x16 sacc;
#pragma unroll
            for (int rr = 0; rr < 16; ++rr) sacc[rr] = 0.f;
            __builtin_amdgcn_s_setprio(1);
#pragma unroll
            for (int ds = 0; ds < 4; ++ds)
                sacc = __builtin_amdgcn_mfma_f32_32x32x16_bf16(kf[ds], qf[ds], sacc, 0, 0, 0);
            __builtin_amdgcn_s_setprio(0);

            float p[16];
#pragma unroll
            for (int reg = 0; reg < 16; ++reg) {
                const int krel = (reg & 3) + 8 * (reg >> 2);
                float d = gq - (float)krel;
                float s2 = fmaf(SLOPE2N, fabsf(d), sacc[reg]);
                float e = fast_exp2(s2);
                p[reg] = e;
                ps[reg & 3] += e;
            }

            __builtin_amdgcn_s_setprio(1);
#pragma unroll
            for (int ks = 0; ks < 2; ++ks) {
                unsigned u0 = pkbf16(p[8 * ks + 0], p[8 * ks + 1]);
                unsigned u1 = pkbf16(p[8 * ks + 2], p[8 * ks + 3]);
                unsigned v0 = pkbf16(p[8 * ks + 4], p[8 * ks + 5]);
                unsigned v1 = pkbf16(p[8 * ks + 6], p[8 * ks + 7]);
                plswap(u0, v0);
                plswap(u1, v1);
                FragU pf; pf.u = (uint4v){u0, u1, v0, v1};
#pragma unroll
                for (int dblk = 0; dblk < 2; ++dblk)
                    oa[dblk] = __builtin_amdgcn_mfma_f32_32x32x16_bf16(vf[dblk * 2 + ks], pf.b, oa[dblk], 0, 0, 0);
            }
            __builtin_amdgcn_s_setprio(0);
        }
    };

    // ---- 2-deep software pipeline over my parity's tiles ----
    {
        bf16x8 kA[4], vA[4], kB[4], vB[4];
        int t = tmin + par;
        if (t <= tmax) {
            const int n = ((tmax - t) >> lgs) + 1;
            LOADF(kA, vA, t);
            int i = 0;
            while (i + 2 <= n) {
                LOADF(kB, vB, t + stride);
                asm volatile("s_waitcnt vmcnt(8)" ::: "memory");   // kA/vA landed
                __builtin_amdgcn_sched_barrier(0);
                COMPUTE(kA, vA, t);
                if (i + 2 < n) {
                    LOADF(kA, vA, t + 2 * stride);
                    asm volatile("s_waitcnt vmcnt(8)" ::: "memory"); // kB/vB landed
                } else {
                    asm volatile("s_waitcnt vmcnt(0)" ::: "memory");
                }
                __builtin_amdgcn_sched_barrier(0);
                COMPUTE(kB, vB, t + stride);
                t += 2 * stride; i += 2;
            }
            if (i < n) {
                asm volatile("s_waitcnt vmcnt(0)" ::: "memory");
                __builtin_amdgcn_sched_barrier(0);
                COMPUTE(kA, vA, t);
            }
        }
    }

    // ---- combine: heavy = 8-wave tree, light = per-group 4-wave tree ----
    float psumA = (psA[0] + psA[1]) + (psA[2] + psA[3]);
    psumA += __shfl_xor(psumA, 32);
    float psumB = (psB[0] + psB[1]) + (psB[2] + psB[3]);
    psumB += __shfl_xor(psumB, 32);

    auto WRITE = [&](int si) {
        float* s = &ex[si][lane][0];
#pragma unroll
        for (int dblk = 0; dblk < 2; ++dblk)
#pragma unroll
            for (int g2 = 0; g2 < 4; ++g2) {
                *(float4*)(s + dblk * 16 + g2 * 4) =
                    (float4){oaccA[dblk][4*g2+0], oaccA[dblk][4*g2+1],
                             oaccA[dblk][4*g2+2], oaccA[dblk][4*g2+3]};
                *(float4*)(s + 36 + dblk * 16 + g2 * 4) =
                    (float4){oaccB[dblk][4*g2+0], oaccB[dblk][4*g2+1],
                             oaccB[dblk][4*g2+2], oaccB[dblk][4*g2+3]};
            }
        s[32] = psumA;
        s[68] = psumB;
    };
    auto ADDIN = [&](int si) {
        const float* s = &ex[si][lane][0];
#pragma unroll
        for (int dblk = 0; dblk < 2; ++dblk)
#pragma unroll
            for (int g2 = 0; g2 < 4; ++g2) {
                float4 oa = *(const float4*)(s + dblk * 16 + g2 * 4);
                float4 ob = *(const float4*)(s + 36 + dblk * 16 + g2 * 4);
                oaccA[dblk][4*g2+0] += oa.x; oaccA[dblk][4*g2+1] += oa.y;
                oaccA[dblk][4*g2+2] += oa.z; oaccA[dblk][4*g2+3] += oa.w;
                oaccB[dblk][4*g2+0] += ob.x; oaccB[dblk][4*g2+1] += ob.y;
                oaccB[dblk][4*g2+2] += ob.z; oaccB[dblk][4*g2+3] += ob.w;
            }
        psumA += s[32];
        psumB += s[68];
    };

    const int sb4 = (wave >> 2) * 2;          // light group slot base
    // L1: odd parities write slot par>>1 (heavy: 0..3, light: sb4+0/1)
    if (par & 1) WRITE(heavy ? (par >> 1) : (sb4 + (par >> 1)));
    __syncthreads();
    if (!(par & 1)) ADDIN(heavy ? (par >> 1) : (sb4 + (par >> 1)));
    __syncthreads();
    // L2
    if (heavy ? (par == 2 || par == 6) : (par == 2)) WRITE(heavy ? (par >> 2) : sb4);
    __syncthreads();
    if (heavy ? (par == 0 || par == 4) : (par == 0)) ADDIN(heavy ? (par >> 2) : sb4);
    __syncthreads();
    // L3 (heavy only)
    if (heavy && par == 4) WRITE(0);
    __syncthreads();
    if (par == 0) {
        if (heavy) ADDIN(0);
        const float invA = 1.f / psumA;
        const float invB = 1.f / psumB;
#pragma unroll
        for (int dblk = 0; dblk < 2; ++dblk)
#pragma unroll
            for (int g2 = 0; g2 < 4; ++g2) {
                float4 oa = {oaccA[dblk][4*g2+0] * invA, oaccA[dblk][4*g2+1] * invA,
                             oaccA[dblk][4*g2+2] * invA, oaccA[dblk][4*g2+3] * invA};
                *(float4*)(Op + (size_t)qrowA * DH + dblk * 32 + g2 * 8 + hi * 4) = oa;
                float4 ob = {oaccB[dblk][4*g2+0] * invB, oaccB[dblk][4*g2+1] * invB,
                             oaccB[dblk][4*g2+2] * invB, oaccB[dblk][4*g2+3] * invB};
                *(float4*)(Op + (size_t)(qrowA + 32) * DH + dblk * 32 + g2 * 8 + hi * 4) = ob;
            }
    }
}

extern "C" void kernel_launch(void* const* d_in, const int* in_sizes, int n_in,
                              void* d_out, int out_size, void* d_ws, size_t ws_size,
                              hipStream_t stream) {
    const float* q = (const float*)d_in[0];
    const float* k = (const float*)d_in[1];
    const float* v = (const float*)d_in[2];
    float* out = (float*)d_out;
    char* W = (char*)d_ws;                    // 32 bh x 64 tiles x 8KB = 16 MB
    alibi_prep_kernel<<<dim3(SQ / 64, 2 * NH, 2), dim3(256), 0, stream>>>(k, v, W);
    alibi_attn_kernel<<<dim3(HEAVY_BLOCKS + LIGHT_BLOCKS), dim3(512), 0, stream>>>(q, W, out);
}

// Round 17
// 49.777 us; speedup vs baseline: 7.3434x; 1.1053x over previous
//
#include <hip/hip_runtime.h>
#include <hip/hip_bf16.h>
#include <math.h>

typedef __bf16 bf16;
typedef __attribute__((ext_vector_type(8))) bf16 bf16x8;
typedef __attribute__((ext_vector_type(2))) bf16 bf16x2;
typedef __attribute__((ext_vector_type(16))) float f32x16;
typedef __attribute__((ext_vector_type(4))) unsigned int uint4v;

#define SQ 2048
#define DH 64
#define NH 16
#define KVT 32
#define NKVT (SQ / KVT)          // 64 tiles per bh
#define REC 8192                 // per-tile record: 4KB K-frags + 4KB V-frags
#define LOG2E 1.44269504088896340736f
#define NITEMS 1024              // (bh, 64q-chunk) work items
#define GRID 640
#define THETA 14.0f              // band cutoff in exp2 domain (rel err ~2.5e-3 worst case)

__device__ __forceinline__ float fast_exp2(float x) {
#if __has_builtin(__builtin_amdgcn_exp2f)
    return __builtin_amdgcn_exp2f(x);
#else
    return exp2f(x);
#endif
}

__device__ __forceinline__ unsigned pkbf16(float a, float b) {
    union { bf16x2 h; unsigned u; } x;
    x.h = (bf16x2){(bf16)a, (bf16)b};
    return x.u;
}

#if __has_builtin(__builtin_amdgcn_permlane32_swap)
__device__ __forceinline__ void plswap(unsigned &a, unsigned &b) {
    typedef __attribute__((ext_vector_type(2))) unsigned int uint2v;
    uint2v r = __builtin_amdgcn_permlane32_swap(a, b, false, false);
    a = r[0]; b = r[1];
}
#else
__device__ __forceinline__ void plswap(unsigned &a, unsigned &b) {
    asm volatile("v_permlane32_swap_b32 %0, %1" : "+v"(a), "+v"(b));
}
#endif

union FragU { uint4v u; bf16x8 b; };

// ---------- prepass: write K and V as pre-fragmented 8KB tile records ----------
__global__ __launch_bounds__(256)
void alibi_prep_kernel(const float* __restrict__ K, const float* __restrict__ V,
                       char* __restrict__ W, int* __restrict__ ctr) {
    __shared__ bf16 lt[64][80];
    const int t  = threadIdx.x;
    const int s0 = blockIdx.x * 64;   // 64 kv rows = 2 tiles
    const int bh = blockIdx.y;
    if (ctr && blockIdx.x == 0 && blockIdx.y == 0 && blockIdx.z == 0 && t == 0)
        *ctr = 0;                     // zero the work-queue counter each launch
    if (blockIdx.z == 0) {
#pragma unroll
        for (int i = 0; i < 2; ++i) {
            const int g    = i * 256 + t;
            const int tile = g >> 8;
            const int cc   = g & 255;
            const int ds   = cc >> 6;
            const int lane = cc & 63;
            const float* p = K + ((size_t)bh * SQ + s0 + tile * 32 + (lane & 31)) * DH
                               + ds * 16 + (lane >> 5) * 8;
            float4 a = *(const float4*)p, b = *(const float4*)(p + 4);
            bf16x8 pk = {(bf16)a.x,(bf16)a.y,(bf16)a.z,(bf16)a.w,
                         (bf16)b.x,(bf16)b.y,(bf16)b.z,(bf16)b.w};
            *(bf16x8*)(W + (size_t)(bh * NKVT + (s0 >> 5) + tile) * REC
                         + ds * 1024 + lane * 16) = pk;
        }
    } else {
#pragma unroll
        for (int i = 0; i < 2; ++i) {
            int idx = i * 256 + t;
            int row = idx >> 3, c8 = idx & 7;
            const float* p = V + ((size_t)bh * SQ + s0 + row) * DH + c8 * 8;
            float4 a = *(const float4*)p, b = *(const float4*)(p + 4);
            bf16 e[8] = {(bf16)a.x,(bf16)a.y,(bf16)a.z,(bf16)a.w,
                         (bf16)b.x,(bf16)b.y,(bf16)b.z,(bf16)b.w};
#pragma unroll
            for (int jj = 0; jj < 8; ++jj) lt[c8 * 8 + jj][row] = e[jj];
        }
        __syncthreads();
#pragma unroll
        for (int i = 0; i < 2; ++i) {
            const int g    = i * 256 + t;
            const int tile = g >> 8;
            const int cc   = g & 255;
            const int grp  = cc >> 6;
            const int lane = cc & 63;
            const int d    = (grp >> 1) * 32 + (lane & 31);
            const int sv   = tile * 32 + (grp & 1) * 16 + (lane >> 5) * 8;
            bf16x8 v = *(const bf16x8*)&lt[d][sv];
            *(bf16x8*)(W + (size_t)(bh * NKVT + (s0 >> 5) + tile) * REC
                         + 4096 + grp * 1024 + lane * 16) = v;
        }
    }
}

// ---------- main attention: dynamic heavy-first work queue, R14 compute core ----------
__global__ __launch_bounds__(256, 2)
void alibi_attn_kernel(const float* __restrict__ Q, const char* __restrict__ W,
                       float* __restrict__ Out, int* __restrict__ ctr) {
    __shared__ float ex[2][64][72];   // 4-parity combine slots (36.9 KB)
    __shared__ int s_id;
    const int tid  = threadIdx.x;
    const int lane = tid & 63;
    const int par  = tid >> 6;        // kv parity 0..3
    const int r32  = lane & 31;
    const int hi   = lane >> 5;
    const float QSCALE = 0.125f * LOG2E;

    int next_static = blockIdx.x;     // fallback when no queue counter available

    while (true) {
        // ---- pop next work item (heavy-first rank order) ----
        if (tid == 0) s_id = ctr ? atomicAdd(ctr, 1) : next_static;
        __syncthreads();              // also fences ex reuse across items
        const int r = s_id;
        next_static += GRID;
        if (r >= NITEMS) break;

        // rank -> (h desc by band width, batch, q-chunk)
        const int h   = 15 - (r >> 6);
        const int sub = r & 63;
        const int bh  = (sub >> 5) * NH + h;
        const int q0  = (sub & 31) * 64;

        const float slope2  = exp2f(-0.5f * (float)(h + 1)) * LOG2E;
        const float SLOPE2N = -slope2;
        const int D = (int)(THETA / slope2);
        const int a0 = q0 - D;
        const int tmin = (a0 <= 0) ? 0 : (a0 >> 5);
        const int tmax = min(NKVT - 1, (q0 + 63 + D) >> 5);

        const float* Qp = Q + (size_t)bh * SQ * DH;
        float*       Op = Out + (size_t)bh * SQ * DH;
        const char*  rec = W + (size_t)bh * NKVT * REC;

        // Q fragments, two q-sets: A rows q0+r32, B rows q0+32+r32
        const int qrowA = q0 + r32;
        bf16x8 qfragA[4], qfragB[4];
#pragma unroll
        for (int ds = 0; ds < 4; ++ds) {
            const float* sa = Qp + (size_t)qrowA * DH + ds * 16 + hi * 8;
            float4 a = *(const float4*)sa, b = *(const float4*)(sa + 4);
            qfragA[ds] = (bf16x8){(bf16)(a.x*QSCALE),(bf16)(a.y*QSCALE),
                                  (bf16)(a.z*QSCALE),(bf16)(a.w*QSCALE),
                                  (bf16)(b.x*QSCALE),(bf16)(b.y*QSCALE),
                                  (bf16)(b.z*QSCALE),(bf16)(b.w*QSCALE)};
            const float* sb = sa + 32 * DH;
            float4 c = *(const float4*)sb, d = *(const float4*)(sb + 4);
            qfragB[ds] = (bf16x8){(bf16)(c.x*QSCALE),(bf16)(c.y*QSCALE),
                                  (bf16)(c.z*QSCALE),(bf16)(c.w*QSCALE),
                                  (bf16)(d.x*QSCALE),(bf16)(d.y*QSCALE),
                                  (bf16)(d.z*QSCALE),(bf16)(d.w*QSCALE)};
        }

        f32x16 oaccA[2], oaccB[2];
#pragma unroll
        for (int d2 = 0; d2 < 2; ++d2)
#pragma unroll
            for (int rr = 0; rr < 16; ++rr) { oaccA[d2][rr] = 0.f; oaccB[d2][rr] = 0.f; }
        float psA[4] = {0.f,0.f,0.f,0.f}, psB[4] = {0.f,0.f,0.f,0.f};
        const float qhA = (float)(qrowA - 4 * hi);

        auto LOADF = [&](bf16x8* kf, bf16x8* vf, int tt) {
            const char* rb = rec + (size_t)tt * REC + lane * 16;
#pragma unroll
            for (int ds = 0; ds < 4; ++ds) kf[ds] = *(const bf16x8*)(rb + ds * 1024);
#pragma unroll
            for (int g = 0; g < 4; ++g)    vf[g] = *(const bf16x8*)(rb + 4096 + g * 1024);
        };

        auto COMPUTE = [&](const bf16x8* kf, const bf16x8* vf, int tt) {
            const float gq0 = qhA - (float)(tt * KVT);
#pragma unroll
            for (int qs = 0; qs < 2; ++qs) {
                const bf16x8* qf = qs ? qfragB : qfragA;
                f32x16*       oa = qs ? oaccB  : oaccA;
                float*        ps = qs ? psB    : psA;
                const float   gq = qs ? gq0 + 32.f : gq0;

                f32x16 sacc;
#pragma unroll
                for (int rr = 0; rr < 16; ++rr) sacc[rr] = 0.f;
                __builtin_amdgcn_s_setprio(1);
#pragma unroll
                for (int ds = 0; ds < 4; ++ds)
                    sacc = __builtin_amdgcn_mfma_f32_32x32x16_bf16(kf[ds], qf[ds], sacc, 0, 0, 0);
                __builtin_amdgcn_s_setprio(0);

                float p[16];
#pragma unroll
                for (int reg = 0; reg < 16; ++reg) {
                    const int krel = (reg & 3) + 8 * (reg >> 2);
                    float d = gq - (float)krel;
                    float s2 = fmaf(SLOPE2N, fabsf(d), sacc[reg]);
                    float e = fast_exp2(s2);
                    p[reg] = e;
                    ps[reg & 3] += e;
                }

                __builtin_amdgcn_s_setprio(1);
#pragma unroll
                for (int ks = 0; ks < 2; ++ks) {
                    unsigned u0 = pkbf16(p[8 * ks + 0], p[8 * ks + 1]);
                    unsigned u1 = pkbf16(p[8 * ks + 2], p[8 * ks + 3]);
                    unsigned v0 = pkbf16(p[8 * ks + 4], p[8 * ks + 5]);
                    unsigned v1 = pkbf16(p[8 * ks + 6], p[8 * ks + 7]);
                    plswap(u0, v0);
                    plswap(u1, v1);
                    FragU pf; pf.u = (uint4v){u0, u1, v0, v1};
#pragma unroll
                    for (int dblk = 0; dblk < 2; ++dblk)
                        oa[dblk] = __builtin_amdgcn_mfma_f32_32x32x16_bf16(vf[dblk * 2 + ks], pf.b, oa[dblk], 0, 0, 0);
                }
                __builtin_amdgcn_s_setprio(0);
            }
        };

        // ---- 2-deep software pipeline over my parity's tiles (stride 4) ----
        {
            bf16x8 kA[4], vA[4], kB[4], vB[4];
            int t = tmin + par;
            if (t <= tmax) {
                const int n = ((tmax - t) >> 2) + 1;
                LOADF(kA, vA, t);
                int i = 0;
                while (i + 2 <= n) {
                    LOADF(kB, vB, t + 4);
                    asm volatile("s_waitcnt vmcnt(8)" ::: "memory");   // kA/vA landed
                    __builtin_amdgcn_sched_barrier(0);
                    COMPUTE(kA, vA, t);
                    if (i + 2 < n) {
                        LOADF(kA, vA, t + 8);
                        asm volatile("s_waitcnt vmcnt(8)" ::: "memory"); // kB/vB landed
                    } else {
                        asm volatile("s_waitcnt vmcnt(0)" ::: "memory");
                    }
                    __builtin_amdgcn_sched_barrier(0);
                    COMPUTE(kB, vB, t + 4);
                    t += 8; i += 2;
                }
                if (i < n) {
                    asm volatile("s_waitcnt vmcnt(0)" ::: "memory");
                    __builtin_amdgcn_sched_barrier(0);
                    COMPUTE(kA, vA, t);
                }
            }
        }

        // ---- combine 4 parities (tree via 2 LDS slots, 3 barriers) ----
        float psumA = (psA[0] + psA[1]) + (psA[2] + psA[3]);
        psumA += __shfl_xor(psumA, 32);
        float psumB = (psB[0] + psB[1]) + (psB[2] + psB[3]);
        psumB += __shfl_xor(psumB, 32);

        auto WRITE = [&](int si) {
            float* s = &ex[si][lane][0];
#pragma unroll
            for (int dblk = 0; dblk < 2; ++dblk)
#pragma unroll
                for (int g2 = 0; g2 < 4; ++g2) {
                    *(float4*)(s + dblk * 16 + g2 * 4) =
                        (float4){oaccA[dblk][4*g2+0], oaccA[dblk][4*g2+1],
                                 oaccA[dblk][4*g2+2], oaccA[dblk][4*g2+3]};
                    *(float4*)(s + 36 + dblk * 16 + g2 * 4) =
                        (float4){oaccB[dblk][4*g2+0], oaccB[dblk][4*g2+1],
                                 oaccB[dblk][4*g2+2], oaccB[dblk][4*g2+3]};
                }
            s[32] = psumA;
            s[68] = psumB;
        };
        auto ADDIN = [&](int si) {
            const float* s = &ex[si][lane][0];
#pragma unroll
            for (int dblk = 0; dblk < 2; ++dblk)
#pragma unroll
                for (int g2 = 0; g2 < 4; ++g2) {
                    float4 oa = *(const float4*)(s + dblk * 16 + g2 * 4);
                    float4 ob = *(const float4*)(s + 36 + dblk * 16 + g2 * 4);
                    oaccA[dblk][4*g2+0] += oa.x; oaccA[dblk][4*g2+1] += oa.y;
                    oaccA[dblk][4*g2+2] += oa.z; oaccA[dblk][4*g2+3] += oa.w;
                    oaccB[dblk][4*g2+0] += ob.x; oaccB[dblk][4*g2+1] += ob.y;
                    oaccB[dblk][4*g2+2] += ob.z; oaccB[dblk][4*g2+3] += ob.w;
                }
            psumA += s[32];
            psumB += s[68];
        };

        if (par & 1) WRITE(par >> 1);          // par1 -> slot0, par3 -> slot1
        __syncthreads();
        if (!(par & 1)) ADDIN(par >> 1);       // par0 += slot0, par2 += slot1
        __syncthreads();
        if (par == 2) WRITE(0);                // combined par2 -> slot0
        __syncthreads();
        if (par == 0) {
            ADDIN(0);
            const float invA = 1.f / psumA;
            const float invB = 1.f / psumB;
#pragma unroll
            for (int dblk = 0; dblk < 2; ++dblk)
#pragma unroll
                for (int g2 = 0; g2 < 4; ++g2) {
                    float4 oa = {oaccA[dblk][4*g2+0] * invA, oaccA[dblk][4*g2+1] * invA,
                                 oaccA[dblk][4*g2+2] * invA, oaccA[dblk][4*g2+3] * invA};
                    *(float4*)(Op + (size_t)qrowA * DH + dblk * 32 + g2 * 8 + hi * 4) = oa;
                    float4 ob = {oaccB[dblk][4*g2+0] * invB, oaccB[dblk][4*g2+1] * invB,
                                 oaccB[dblk][4*g2+2] * invB, oaccB[dblk][4*g2+3] * invB};
                    *(float4*)(Op + (size_t)(qrowA + 32) * DH + dblk * 32 + g2 * 8 + hi * 4) = ob;
                }
        }
    }
}

extern "C" void kernel_launch(void* const* d_in, const int* in_sizes, int n_in,
                              void* d_out, int out_size, void* d_ws, size_t ws_size,
                              hipStream_t stream) {
    const float* q = (const float*)d_in[0];
    const float* k = (const float*)d_in[1];
    const float* v = (const float*)d_in[2];
    float* out = (float*)d_out;
    char* W = (char*)d_ws;                    // 32 bh x 64 tiles x 8KB = 16 MB
    const size_t rec_bytes = (size_t)32 * NKVT * REC;
    int* ctr = (ws_size >= rec_bytes + 4) ? (int*)((char*)d_ws + rec_bytes) : nullptr;
    alibi_prep_kernel<<<dim3(SQ / 64, 2 * NH, 2), dim3(256), 0, stream>>>(k, v, W, ctr);
    alibi_attn_kernel<<<dim3(GRID), dim3(256), 0, stream>>>(q, W, out, ctr);
}